// Round 9
// baseline (294.805 us; speedup 1.0000x reference)
//
#include <hip/hip_runtime.h>
#include <hip/hip_bf16.h>

#define NN 100000
#define NE 1600000
#define NBUCK 391   // ceil(NN / 256)
#define CAP 5120    // per-bucket edge capacity (expected 4096, sigma~64)
#define CHUNK 2048
#define PBLOCKS 782   // ceil(NE / CHUNK)
#define MMBLOCKS 1563 // ceil(NN / 64)

typedef __attribute__((ext_vector_type(8))) short short8;
typedef __attribute__((ext_vector_type(4))) float f32x4;

static __device__ __forceinline__ unsigned short f2bf(float f) {
    unsigned u = __float_as_uint(f);
    unsigned r = (u + 0x7fffu + ((u >> 16) & 1u)) >> 16;
    return (unsigned short)r;
}
static __device__ __forceinline__ float bf_lo(unsigned u) {
    return __uint_as_float(u << 16);
}
static __device__ __forceinline__ float bf_hi(unsigned u) {
    return __uint_as_float(u & 0xffff0000u);
}
static __device__ __forceinline__ void acc8(float* acc, uint4 v, float nm) {
    acc[0] += bf_lo(v.x) * nm; acc[1] += bf_hi(v.x) * nm;
    acc[2] += bf_lo(v.y) * nm; acc[3] += bf_hi(v.y) * nm;
    acc[4] += bf_lo(v.z) * nm; acc[5] += bf_hi(v.z) * nm;
    acc[6] += bf_lo(v.w) * nm; acc[7] += bf_hi(v.w) * nm;
}

// ---------- FAT: blocks [0,PBLOCKS) = partition+degree; rest = x@W1 ----------
// bucket = dst >> 8; pack = (src<<8)|(dst&255)
__global__ __launch_bounds__(256) void k_fat(const int* __restrict__ ei,
                                             int* __restrict__ bcur,
                                             unsigned* __restrict__ ebuf,
                                             int* __restrict__ deg,
                                             const float* __restrict__ x,
                                             const float* __restrict__ W1,
                                             unsigned short* __restrict__ hout) {
    __shared__ unsigned char smem[17408];  // max(mm Wt 64*136*2, partition 2*391*4)
    int tid = threadIdx.x;
    if (blockIdx.x < PBLOCKS) {
        int* lh = (int*)smem;
        int* lbase = lh + NBUCK;
        int e0 = blockIdx.x * CHUNK;
        for (int i = tid; i < NBUCK; i += 256) lh[i] = 0;
        __syncthreads();
        #pragma unroll
        for (int k = 0; k < CHUNK; k += 256) {
            int e = e0 + k + tid;
            if (e < NE) {
                int d = ei[NE + e];
                atomicAdd(&lh[d >> 8], 1);
                atomicAdd(&deg[d], 1);   // global degree histogram (overlapped)
            }
        }
        __syncthreads();
        for (int i = tid; i < NBUCK; i += 256) {
            int c = lh[i];
            lbase[i] = c ? atomicAdd(&bcur[i], c) : 0;  // within-bucket offset
            lh[i] = 0;  // becomes local rank counter
        }
        __syncthreads();
        #pragma unroll
        for (int k = 0; k < CHUNK; k += 256) {
            int e = e0 + k + tid;
            if (e < NE) {
                int d = ei[NE + e];
                int s = ei[e];
                int b = d >> 8;
                int r = atomicAdd(&lh[b], 1);
                int pos = lbase[b] + r;
                if (pos < CAP)  // safety clamp; never hit for uniform input
                    ebuf[(long)b * CAP + pos] = ((unsigned)s << 8) | (unsigned)(d & 255);
            }
        }
    } else {
        // ---- mm128: h1 = x @ W1 -> bf16 ----
        constexpr int K = 128, KP = K + 8;
        unsigned short* Wt = (unsigned short*)smem;  // 64 * 136
        for (int idx = tid; idx < K * 64; idx += 256) {
            int k = idx >> 6, n = idx & 63;
            Wt[n * KP + k] = f2bf(W1[idx]);
        }
        __syncthreads();
        int wave = tid >> 6, lane = tid & 63;
        int m = lane & 15, q = lane >> 4;
        int n0 = (blockIdx.x - PBLOCKS) * 64 + wave * 16;
        f32x4 acc[4] = {{0.f,0.f,0.f,0.f},{0.f,0.f,0.f,0.f},{0.f,0.f,0.f,0.f},{0.f,0.f,0.f,0.f}};
        int row = n0 + m;
        int rowc = row < NN ? row : NN - 1;
        const float* xr = x + (long)rowc * K;
        #pragma unroll
        for (int kk = 0; kk < K / 32; ++kk) {
            const float4* p = (const float4*)(xr + kk * 32 + q * 8);
            float4 v0 = p[0], v1 = p[1];
            float xv[8] = {v0.x, v0.y, v0.z, v0.w, v1.x, v1.y, v1.z, v1.w};
            short8 afrag;
            #pragma unroll
            for (int i2 = 0; i2 < 8; ++i2) afrag[i2] = (short)f2bf(xv[i2]);
            #pragma unroll
            for (int nt = 0; nt < 4; ++nt) {
                const short8* bp = (const short8*)&Wt[(nt * 16 + m) * KP + kk * 32 + q * 8];
                acc[nt] = __builtin_amdgcn_mfma_f32_16x16x32_bf16(afrag, *bp, acc[nt], 0, 0, 0);
            }
        }
        // D layout: col=lane&15, row=(lane>>4)*4+reg  [m89-verified]
        #pragma unroll
        for (int reg = 0; reg < 4; ++reg) {
            int node = n0 + q * 4 + reg;
            if (node < NN) {
                #pragma unroll
                for (int nt = 0; nt < 4; ++nt)
                    hout[(long)node * 64 + nt * 16 + m] = f2bf(acc[nt][reg]);
            }
        }
    }
}

// ---------- dinv[i] = rsqrt(deg[i]+1), in place over deg ----------
__global__ __launch_bounds__(256) void k_dinv(int* __restrict__ deg) {
    int i = blockIdx.x * 256 + threadIdx.x;
    if (i < NN) {
        float dv = rsqrtf((float)deg[i] + 1.0f);
        ((float*)deg)[i] = dv;
    }
}

// one block (256 thr) per bucket: count -> shfl-scan -> rowinfo -> scatter
// rowinfo[node] = (start << 11) | degree; epair[pos] = {src, bits(dinv[src])}
__global__ __launch_bounds__(256) void k_build(const int* __restrict__ bcur,
                                               const unsigned* __restrict__ ebuf,
                                               const float* __restrict__ dinv,
                                               unsigned* __restrict__ rowinfo,
                                               int2* __restrict__ epair) {
    __shared__ int cnt[256];
    __shared__ int wsum[4];
    int tid = threadIdx.x;
    int base = blockIdx.x * CAP;
    int nedge = bcur[blockIdx.x];
    if (nedge > CAP) nedge = CAP;
    cnt[tid] = 0;
    __syncthreads();
    for (int j = tid; j < nedge; j += 256)
        atomicAdd(&cnt[ebuf[base + j] & 255u], 1);
    __syncthreads();
    int v = cnt[tid];
    int lane = tid & 63;
    int incl = v;
    #pragma unroll
    for (int off = 1; off < 64; off <<= 1) {
        int t = __shfl_up(incl, off, 64);
        if (lane >= off) incl += t;
    }
    if (lane == 63) wsum[tid >> 6] = incl;
    __syncthreads();
    if (tid == 0) {
        int a = 0;
        #pragma unroll
        for (int w = 0; w < 4; ++w) { int t = wsum[w]; wsum[w] = a; a += t; }
    }
    __syncthreads();
    int ex = incl - v + wsum[tid >> 6];
    int node = blockIdx.x * 256 + tid;
    if (node < NN)
        rowinfo[node] = ((unsigned)(base + ex) << 11) | (unsigned)v;
    cnt[tid] = base + ex;  // becomes cursor
    __syncthreads();
    for (int j = tid; j < nedge; j += 256) {
        unsigned p = ebuf[base + j];
        int s = (int)(p >> 8);
        int pos = atomicAdd(&cnt[p & 255u], 1);
        epair[pos] = make_int2(s, __float_as_int(dinv[s]));
    }
}

// ---------- layer-2 matmul: h = in(bf16) @ W -> bf16 ----------
__global__ __launch_bounds__(256) void k_mm64(const unsigned short* __restrict__ in_,
                                              const float* __restrict__ W,
                                              unsigned short* __restrict__ hout) {
    constexpr int K = 64, KP = K + 8;
    __shared__ unsigned short Wt[64 * KP];
    int tid = threadIdx.x;
    for (int idx = tid; idx < K * 64; idx += 256) {
        int k = idx >> 6, n = idx & 63;
        Wt[n * KP + k] = f2bf(W[idx]);
    }
    __syncthreads();
    int wave = tid >> 6, lane = tid & 63;
    int m = lane & 15, q = lane >> 4;
    int n0 = blockIdx.x * 64 + wave * 16;
    f32x4 acc[4] = {{0.f,0.f,0.f,0.f},{0.f,0.f,0.f,0.f},{0.f,0.f,0.f,0.f},{0.f,0.f,0.f,0.f}};
    int row = n0 + m;
    int rowc = row < NN ? row : NN - 1;
    const unsigned short* xr = in_ + (long)rowc * K;
    #pragma unroll
    for (int kk = 0; kk < K / 32; ++kk) {
        short8 afrag = *(const short8*)(xr + kk * 32 + q * 8);
        #pragma unroll
        for (int nt = 0; nt < 4; ++nt) {
            const short8* bp = (const short8*)&Wt[(nt * 16 + m) * KP + kk * 32 + q * 8];
            acc[nt] = __builtin_amdgcn_mfma_f32_16x16x32_bf16(afrag, *bp, acc[nt], 0, 0, 0);
        }
    }
    #pragma unroll
    for (int reg = 0; reg < 4; ++reg) {
        int node = n0 + q * 4 + reg;
        if (node < NN) {
            #pragma unroll
            for (int nt = 0; nt < 4; ++nt)
                hout[(long)node * 64 + nt * 16 + m] = f2bf(acc[nt][reg]);
        }
    }
}

// ---------- per-node aggregation: 8 lanes/node, no dinv gather --------------
template <bool OUT_BF16>
__global__ __launch_bounds__(256) void k_agg(const unsigned* __restrict__ rowinfo,
                                             const int2* __restrict__ epair,
                                             const unsigned short* __restrict__ h,
                                             const float* __restrict__ bias,
                                             const float* __restrict__ alpha,
                                             void* __restrict__ out_) {
    int sl = threadIdx.x & 7;          // 8 bf16 columns per lane
    int node = blockIdx.x * 32 + (threadIdx.x >> 3);
    if (node >= NN) return;
    unsigned u = rowinfo[node];
    int start = (int)(u >> 11);
    int cnt = (int)(u & 2047u);
    float dn = rsqrtf((float)cnt + 1.0f);
    const unsigned short* hc = h + sl * 8;

    float acc[8];
    {   // self-loop: norm = dn^2
        uint4 hw = *(const uint4*)(hc + (long)node * 64);
        float d2 = dn * dn;
        acc[0] = bf_lo(hw.x) * d2; acc[1] = bf_hi(hw.x) * d2;
        acc[2] = bf_lo(hw.y) * d2; acc[3] = bf_hi(hw.y) * d2;
        acc[4] = bf_lo(hw.z) * d2; acc[5] = bf_hi(hw.z) * d2;
        acc[6] = bf_lo(hw.w) * d2; acc[7] = bf_hi(hw.w) * d2;
    }

    int i = 0;
    for (; i + 4 <= cnt; i += 4) {
        int2 p0 = epair[start + i];
        int2 p1 = epair[start + i + 1];
        int2 p2 = epair[start + i + 2];
        int2 p3 = epair[start + i + 3];
        float n0 = __int_as_float(p0.y) * dn, n1 = __int_as_float(p1.y) * dn;
        float n2 = __int_as_float(p2.y) * dn, n3 = __int_as_float(p3.y) * dn;
        uint4 w0 = *(const uint4*)(hc + (long)p0.x * 64);
        uint4 w1 = *(const uint4*)(hc + (long)p1.x * 64);
        uint4 w2 = *(const uint4*)(hc + (long)p2.x * 64);
        uint4 w3 = *(const uint4*)(hc + (long)p3.x * 64);
        acc8(acc, w0, n0); acc8(acc, w1, n1); acc8(acc, w2, n2); acc8(acc, w3, n3);
    }
    for (; i < cnt; ++i) {
        int2 p0 = epair[start + i];
        float n0 = __int_as_float(p0.y) * dn;
        uint4 w0 = *(const uint4*)(hc + (long)p0.x * 64);
        acc8(acc, w0, n0);
    }

    // epilogue: bias + PReLU on columns sl*8 .. sl*8+7
    float4 blo = *(const float4*)(bias + sl * 8);
    float4 bhi = *(const float4*)(bias + sl * 8 + 4);
    float4 alo = *(const float4*)(alpha + sl * 8);
    float4 ahi = *(const float4*)(alpha + sl * 8 + 4);
    float bb[8] = {blo.x, blo.y, blo.z, blo.w, bhi.x, bhi.y, bhi.z, bhi.w};
    float aa[8] = {alo.x, alo.y, alo.z, alo.w, ahi.x, ahi.y, ahi.z, ahi.w};
    #pragma unroll
    for (int j = 0; j < 8; ++j) {
        float v = acc[j] + bb[j];
        acc[j] = v >= 0.f ? v : aa[j] * v;
    }

    if (OUT_BF16) {
        uint4 pk;
        pk.x = (unsigned)f2bf(acc[0]) | ((unsigned)f2bf(acc[1]) << 16);
        pk.y = (unsigned)f2bf(acc[2]) | ((unsigned)f2bf(acc[3]) << 16);
        pk.z = (unsigned)f2bf(acc[4]) | ((unsigned)f2bf(acc[5]) << 16);
        pk.w = (unsigned)f2bf(acc[6]) | ((unsigned)f2bf(acc[7]) << 16);
        *(uint4*)((unsigned short*)out_ + (long)node * 64 + sl * 8) = pk;
    } else {
        float* op = (float*)out_ + (long)node * 64 + sl * 8;
        *(float4*)op = make_float4(acc[0], acc[1], acc[2], acc[3]);
        *(float4*)(op + 4) = make_float4(acc[4], acc[5], acc[6], acc[7]);
    }
}

extern "C" void kernel_launch(void* const* d_in, const int* in_sizes, int n_in,
                              void* d_out, int out_size, void* d_ws, size_t ws_size,
                              hipStream_t stream) {
    const float* x     = (const float*)d_in[0];
    const int*   ei    = (const int*)d_in[1];
    const float* W1    = (const float*)d_in[2];
    const float* b1    = (const float*)d_in[3];
    const float* W2    = (const float*)d_in[4];
    const float* b2    = (const float*)d_in[5];
    const float* alpha = (const float*)d_in[6];
    float* out = (float*)d_out;

    char* ws = (char*)d_ws;
    int*      deg       = (int*)(ws);                        //        0: 400,384 (becomes dinv)
    int*      bcur      = (int*)(ws + 400384);               //   400384: 2,048
    unsigned* rowinfo   = (unsigned*)(ws + 402432);          //   402432: 400,384
    int2*     epair     = (int2*)(ws + 802816);              //   802816: 16,015,360 (391*CAP*8)
    unsigned short* hbf = (unsigned short*)(ws + 16818176);  // 16818176: 12,800,000
    unsigned* ebuf      = (unsigned*)(ws + 29618176);        // 29618176: 8,007,680 (dead after build)
    unsigned short* aggbf = (unsigned short*)(ws + 29618176);// alias ebuf: 12,800,000
    // total: 42,418,176 B

    (void)hipMemsetAsync(deg, 0, 402432, stream);  // deg + bcur (contiguous)
    // partition+degree (782 blocks) overlapped with x@W1 (1563 blocks)
    k_fat<<<PBLOCKS + MMBLOCKS, 256, 0, stream>>>(ei, bcur, ebuf, deg, x, W1, hbf);
    k_dinv<<<391, 256, 0, stream>>>(deg);
    k_build<<<NBUCK, 256, 0, stream>>>(bcur, ebuf, (const float*)deg, rowinfo, epair);

    // layer 1 aggregation -> bf16
    k_agg<true><<<(NN + 31) / 32, 256, 0, stream>>>(rowinfo, epair, hbf, b1, alpha, aggbf);
    // layer 2
    k_mm64<<<(NN + 63) / 64, 256, 0, stream>>>(aggbf, W2, hbf);
    k_agg<false><<<(NN + 31) / 32, 256, 0, stream>>>(rowinfo, epair, hbf, b2, alpha, out);
}

// Round 10
// 243.884 us; speedup vs baseline: 1.2088x; 1.2088x over previous
//
#include <hip/hip_runtime.h>
#include <hip/hip_bf16.h>

#define NN 100000
#define NE 1600000
#define NBUCK 391   // ceil(NN / 256)
#define CAP 5120    // per-bucket edge capacity (expected 4096, sigma~64)
#define CHUNK 2048
#define PBLOCKS 782   // ceil(NE / CHUNK)
#define MMBLOCKS 1563 // ceil(NN / 64)

typedef __attribute__((ext_vector_type(8))) short short8;
typedef __attribute__((ext_vector_type(4))) float f32x4;

static __device__ __forceinline__ unsigned short f2bf(float f) {
    unsigned u = __float_as_uint(f);
    unsigned r = (u + 0x7fffu + ((u >> 16) & 1u)) >> 16;
    return (unsigned short)r;
}
static __device__ __forceinline__ float bf_lo(unsigned u) {
    return __uint_as_float(u << 16);
}
static __device__ __forceinline__ float bf_hi(unsigned u) {
    return __uint_as_float(u & 0xffff0000u);
}
static __device__ __forceinline__ void acc8(float* acc, uint4 v, float nm) {
    acc[0] += bf_lo(v.x) * nm; acc[1] += bf_hi(v.x) * nm;
    acc[2] += bf_lo(v.y) * nm; acc[3] += bf_hi(v.y) * nm;
    acc[4] += bf_lo(v.z) * nm; acc[5] += bf_hi(v.z) * nm;
    acc[6] += bf_lo(v.w) * nm; acc[7] += bf_hi(v.w) * nm;
}

// ---------- FAT: blocks [0,PBLOCKS) = edge partition; rest = x@W1 (mm128) ----
// bucket = dst >> 8; pack = (src<<8)|(dst&255). NO global degree histogram.
__global__ __launch_bounds__(256) void k_fat(const int* __restrict__ ei,
                                             int* __restrict__ bcur,
                                             unsigned* __restrict__ ebuf,
                                             const float* __restrict__ x,
                                             const float* __restrict__ W1,
                                             unsigned short* __restrict__ hout) {
    __shared__ __attribute__((aligned(16))) unsigned char smem[17408];  // max(mm Wt 64*136*2=17408, part 2*391*4=3128)
    int tid = threadIdx.x;
    if (blockIdx.x < PBLOCKS) {
        int* lh = (int*)smem;
        int* lbase = lh + NBUCK;
        int e0 = blockIdx.x * CHUNK;
        for (int i = tid; i < NBUCK; i += 256) lh[i] = 0;
        __syncthreads();
        #pragma unroll
        for (int k = 0; k < CHUNK; k += 256) {
            int e = e0 + k + tid;
            if (e < NE) atomicAdd(&lh[ei[NE + e] >> 8], 1);
        }
        __syncthreads();
        for (int i = tid; i < NBUCK; i += 256) {
            int c = lh[i];
            lbase[i] = c ? atomicAdd(&bcur[i], c) : 0;  // within-bucket offset
            lh[i] = 0;  // becomes local rank counter
        }
        __syncthreads();
        #pragma unroll
        for (int k = 0; k < CHUNK; k += 256) {
            int e = e0 + k + tid;
            if (e < NE) {
                int d = ei[NE + e];
                int s = ei[e];
                int b = d >> 8;
                int r = atomicAdd(&lh[b], 1);
                int pos = lbase[b] + r;
                if (pos < CAP)  // safety clamp; never hit for uniform input
                    ebuf[(long)b * CAP + pos] = ((unsigned)s << 8) | (unsigned)(d & 255);
            }
        }
    } else {
        // ---- mm128: h1 = x @ W1 -> bf16 ----
        constexpr int K = 128, KP = K + 8;
        unsigned short* Wt = (unsigned short*)smem;  // 64 * 136
        for (int idx = tid; idx < K * 64; idx += 256) {
            int k = idx >> 6, n = idx & 63;
            Wt[n * KP + k] = f2bf(W1[idx]);
        }
        __syncthreads();
        int wave = tid >> 6, lane = tid & 63;
        int m = lane & 15, q = lane >> 4;
        int n0 = (blockIdx.x - PBLOCKS) * 64 + wave * 16;
        f32x4 acc[4] = {{0.f,0.f,0.f,0.f},{0.f,0.f,0.f,0.f},{0.f,0.f,0.f,0.f},{0.f,0.f,0.f,0.f}};
        int row = n0 + m;
        int rowc = row < NN ? row : NN - 1;
        const float* xr = x + (long)rowc * K;
        #pragma unroll
        for (int kk = 0; kk < K / 32; ++kk) {
            const float4* p = (const float4*)(xr + kk * 32 + q * 8);
            float4 v0 = p[0], v1 = p[1];
            float xv[8] = {v0.x, v0.y, v0.z, v0.w, v1.x, v1.y, v1.z, v1.w};
            short8 afrag;
            #pragma unroll
            for (int i2 = 0; i2 < 8; ++i2) afrag[i2] = (short)f2bf(xv[i2]);
            #pragma unroll
            for (int nt = 0; nt < 4; ++nt) {
                const short8* bp = (const short8*)&Wt[(nt * 16 + m) * KP + kk * 32 + q * 8];
                acc[nt] = __builtin_amdgcn_mfma_f32_16x16x32_bf16(afrag, *bp, acc[nt], 0, 0, 0);
            }
        }
        // D layout: col=lane&15, row=(lane>>4)*4+reg  [m89-verified]
        #pragma unroll
        for (int reg = 0; reg < 4; ++reg) {
            int node = n0 + q * 4 + reg;
            if (node < NN) {
                #pragma unroll
                for (int nt = 0; nt < 4; ++nt)
                    hout[(long)node * 64 + nt * 16 + m] = f2bf(acc[nt][reg]);
            }
        }
    }
}

// one block (256 thr) per bucket: count -> shfl-scan -> rowinfo/dinv -> scatter
// rowinfo[node] = (start << 11) | degree   (start < 391*5120 < 2^21, deg < 2^11)
__global__ __launch_bounds__(256) void k_build(const int* __restrict__ bcur,
                                               const unsigned* __restrict__ ebuf,
                                               unsigned* __restrict__ rowinfo,
                                               float* __restrict__ dinv,
                                               int* __restrict__ esrc) {
    __shared__ int cnt[256];
    __shared__ int wsum[4];
    int tid = threadIdx.x;
    int base = blockIdx.x * CAP;
    int nedge = bcur[blockIdx.x];
    if (nedge > CAP) nedge = CAP;
    cnt[tid] = 0;
    __syncthreads();
    for (int j = tid; j < nedge; j += 256)
        atomicAdd(&cnt[ebuf[base + j] & 255u], 1);
    __syncthreads();
    int v = cnt[tid];
    int lane = tid & 63;
    int incl = v;
    #pragma unroll
    for (int off = 1; off < 64; off <<= 1) {
        int t = __shfl_up(incl, off, 64);
        if (lane >= off) incl += t;
    }
    if (lane == 63) wsum[tid >> 6] = incl;
    __syncthreads();
    if (tid == 0) {
        int a = 0;
        #pragma unroll
        for (int w = 0; w < 4; ++w) { int t = wsum[w]; wsum[w] = a; a += t; }
    }
    __syncthreads();
    int ex = incl - v + wsum[tid >> 6];
    int node = blockIdx.x * 256 + tid;
    if (node < NN) {
        rowinfo[node] = ((unsigned)(base + ex) << 11) | (unsigned)v;
        dinv[node] = rsqrtf((float)(v + 1));  // +1 self-loop
    }
    cnt[tid] = base + ex;  // becomes cursor
    __syncthreads();
    for (int j = tid; j < nedge; j += 256) {
        unsigned p = ebuf[base + j];
        int pos = atomicAdd(&cnt[p & 255u], 1);
        esrc[pos] = (int)(p >> 8);
    }
}

// ---------- layer-2 matmul: h = in(bf16) @ W -> bf16 ----------
__global__ __launch_bounds__(256) void k_mm64(const unsigned short* __restrict__ in_,
                                              const float* __restrict__ W,
                                              unsigned short* __restrict__ hout) {
    constexpr int K = 64, KP = K + 8;
    __shared__ unsigned short Wt[64 * KP];
    int tid = threadIdx.x;
    for (int idx = tid; idx < K * 64; idx += 256) {
        int k = idx >> 6, n = idx & 63;
        Wt[n * KP + k] = f2bf(W[idx]);
    }
    __syncthreads();
    int wave = tid >> 6, lane = tid & 63;
    int m = lane & 15, q = lane >> 4;
    int n0 = blockIdx.x * 64 + wave * 16;
    f32x4 acc[4] = {{0.f,0.f,0.f,0.f},{0.f,0.f,0.f,0.f},{0.f,0.f,0.f,0.f},{0.f,0.f,0.f,0.f}};
    int row = n0 + m;
    int rowc = row < NN ? row : NN - 1;
    const unsigned short* xr = in_ + (long)rowc * K;
    #pragma unroll
    for (int kk = 0; kk < K / 32; ++kk) {
        short8 afrag = *(const short8*)(xr + kk * 32 + q * 8);
        #pragma unroll
        for (int nt = 0; nt < 4; ++nt) {
            const short8* bp = (const short8*)&Wt[(nt * 16 + m) * KP + kk * 32 + q * 8];
            acc[nt] = __builtin_amdgcn_mfma_f32_16x16x32_bf16(afrag, *bp, acc[nt], 0, 0, 0);
        }
    }
    #pragma unroll
    for (int reg = 0; reg < 4; ++reg) {
        int node = n0 + q * 4 + reg;
        if (node < NN) {
            #pragma unroll
            for (int nt = 0; nt < 4; ++nt)
                hout[(long)node * 64 + nt * 16 + m] = f2bf(acc[nt][reg]);
        }
    }
}

// ---------- per-node aggregation: 8 lanes/node, uint4 gathers, unroll-8 ------
template <bool OUT_BF16>
__global__ __launch_bounds__(256) void k_agg(const unsigned* __restrict__ rowinfo,
                                             const int* __restrict__ esrc,
                                             const unsigned short* __restrict__ h,
                                             const float* __restrict__ dinv,
                                             const float* __restrict__ bias,
                                             const float* __restrict__ alpha,
                                             void* __restrict__ out_) {
    int sl = threadIdx.x & 7;          // 8 bf16 columns per lane
    int node = blockIdx.x * 32 + (threadIdx.x >> 3);
    if (node >= NN) return;
    unsigned u = rowinfo[node];
    int start = (int)(u >> 11);
    int cnt = (int)(u & 2047u);
    float dn = dinv[node];
    const unsigned short* hc = h + sl * 8;

    float acc[8];
    {   // self-loop: norm = dn^2
        uint4 hw = *(const uint4*)(hc + (long)node * 64);
        float d2 = dn * dn;
        acc[0] = bf_lo(hw.x) * d2; acc[1] = bf_hi(hw.x) * d2;
        acc[2] = bf_lo(hw.y) * d2; acc[3] = bf_hi(hw.y) * d2;
        acc[4] = bf_lo(hw.z) * d2; acc[5] = bf_hi(hw.z) * d2;
        acc[6] = bf_lo(hw.w) * d2; acc[7] = bf_hi(hw.w) * d2;
    }

    int i = 0;
    for (; i + 8 <= cnt; i += 8) {
        int s0 = esrc[start + i];
        int s1 = esrc[start + i + 1];
        int s2 = esrc[start + i + 2];
        int s3 = esrc[start + i + 3];
        int s4 = esrc[start + i + 4];
        int s5 = esrc[start + i + 5];
        int s6 = esrc[start + i + 6];
        int s7 = esrc[start + i + 7];
        float n0 = dinv[s0] * dn, n1 = dinv[s1] * dn;
        float n2 = dinv[s2] * dn, n3 = dinv[s3] * dn;
        float n4 = dinv[s4] * dn, n5 = dinv[s5] * dn;
        float n6 = dinv[s6] * dn, n7 = dinv[s7] * dn;
        uint4 w0 = *(const uint4*)(hc + (long)s0 * 64);
        uint4 w1 = *(const uint4*)(hc + (long)s1 * 64);
        uint4 w2 = *(const uint4*)(hc + (long)s2 * 64);
        uint4 w3 = *(const uint4*)(hc + (long)s3 * 64);
        uint4 w4 = *(const uint4*)(hc + (long)s4 * 64);
        uint4 w5 = *(const uint4*)(hc + (long)s5 * 64);
        uint4 w6 = *(const uint4*)(hc + (long)s6 * 64);
        uint4 w7 = *(const uint4*)(hc + (long)s7 * 64);
        acc8(acc, w0, n0); acc8(acc, w1, n1); acc8(acc, w2, n2); acc8(acc, w3, n3);
        acc8(acc, w4, n4); acc8(acc, w5, n5); acc8(acc, w6, n6); acc8(acc, w7, n7);
    }
    if (i + 4 <= cnt) {
        int s0 = esrc[start + i];
        int s1 = esrc[start + i + 1];
        int s2 = esrc[start + i + 2];
        int s3 = esrc[start + i + 3];
        float n0 = dinv[s0] * dn, n1 = dinv[s1] * dn;
        float n2 = dinv[s2] * dn, n3 = dinv[s3] * dn;
        uint4 w0 = *(const uint4*)(hc + (long)s0 * 64);
        uint4 w1 = *(const uint4*)(hc + (long)s1 * 64);
        uint4 w2 = *(const uint4*)(hc + (long)s2 * 64);
        uint4 w3 = *(const uint4*)(hc + (long)s3 * 64);
        acc8(acc, w0, n0); acc8(acc, w1, n1); acc8(acc, w2, n2); acc8(acc, w3, n3);
        i += 4;
    }
    for (; i < cnt; ++i) {
        int s0 = esrc[start + i];
        float n0 = dinv[s0] * dn;
        uint4 w0 = *(const uint4*)(hc + (long)s0 * 64);
        acc8(acc, w0, n0);
    }

    // epilogue: bias + PReLU on columns sl*8 .. sl*8+7
    float4 blo = *(const float4*)(bias + sl * 8);
    float4 bhi = *(const float4*)(bias + sl * 8 + 4);
    float4 alo = *(const float4*)(alpha + sl * 8);
    float4 ahi = *(const float4*)(alpha + sl * 8 + 4);
    float bb[8] = {blo.x, blo.y, blo.z, blo.w, bhi.x, bhi.y, bhi.z, bhi.w};
    float aa[8] = {alo.x, alo.y, alo.z, alo.w, ahi.x, ahi.y, ahi.z, ahi.w};
    #pragma unroll
    for (int j = 0; j < 8; ++j) {
        float v = acc[j] + bb[j];
        acc[j] = v >= 0.f ? v : aa[j] * v;
    }

    if (OUT_BF16) {
        uint4 pk;
        pk.x = (unsigned)f2bf(acc[0]) | ((unsigned)f2bf(acc[1]) << 16);
        pk.y = (unsigned)f2bf(acc[2]) | ((unsigned)f2bf(acc[3]) << 16);
        pk.z = (unsigned)f2bf(acc[4]) | ((unsigned)f2bf(acc[5]) << 16);
        pk.w = (unsigned)f2bf(acc[6]) | ((unsigned)f2bf(acc[7]) << 16);
        *(uint4*)((unsigned short*)out_ + (long)node * 64 + sl * 8) = pk;
    } else {
        float* op = (float*)out_ + (long)node * 64 + sl * 8;
        *(float4*)op = make_float4(acc[0], acc[1], acc[2], acc[3]);
        *(float4*)(op + 4) = make_float4(acc[4], acc[5], acc[6], acc[7]);
    }
}

extern "C" void kernel_launch(void* const* d_in, const int* in_sizes, int n_in,
                              void* d_out, int out_size, void* d_ws, size_t ws_size,
                              hipStream_t stream) {
    const float* x     = (const float*)d_in[0];
    const int*   ei    = (const int*)d_in[1];
    const float* W1    = (const float*)d_in[2];
    const float* b1    = (const float*)d_in[3];
    const float* W2    = (const float*)d_in[4];
    const float* b2    = (const float*)d_in[5];
    const float* alpha = (const float*)d_in[6];
    float* out = (float*)d_out;

    char* ws = (char*)d_ws;
    float*    dinv      = (float*)(ws);                      //        0: 400,384
    unsigned* rowinfo   = (unsigned*)(ws + 400384);          //   400384: 400,384
    int*      bcur      = (int*)(ws + 800768);               //   800768: 2,048
    int*      esrc      = (int*)(ws + 802816);               //   802816: 8,007,680 (391*CAP)
    unsigned short* hbf = (unsigned short*)(ws + 8810496);   //  8810496: 12,800,000
    unsigned* ebuf      = (unsigned*)(ws + 21610496);        // 21610496: 8,007,680 (dead after build)
    unsigned short* aggbf = (unsigned short*)(ws + 21610496);// alias ebuf: 12,800,000
    // total: 34,410,496 B

    (void)hipMemsetAsync(bcur, 0, NBUCK * sizeof(int), stream);
    // edge partition (782 blocks) overlapped with x@W1 (1563 blocks)
    k_fat<<<PBLOCKS + MMBLOCKS, 256, 0, stream>>>(ei, bcur, ebuf, x, W1, hbf);
    k_build<<<NBUCK, 256, 0, stream>>>(bcur, ebuf, rowinfo, dinv, esrc);

    // layer 1 aggregation -> bf16
    k_agg<true><<<(NN + 31) / 32, 256, 0, stream>>>(rowinfo, esrc, hbf, dinv, b1, alpha, aggbf);
    // layer 2
    k_mm64<<<(NN + 63) / 64, 256, 0, stream>>>(aggbf, W2, hbf);
    k_agg<false><<<(NN + 31) / 32, 256, 0, stream>>>(rowinfo, esrc, hbf, dinv, b2, alpha, out);
}

// Round 11
// 225.985 us; speedup vs baseline: 1.3045x; 1.0792x over previous
//
#include <hip/hip_runtime.h>
#include <hip/hip_bf16.h>

#define NN 100000
#define NE 1600000
#define NBUCK 391   // ceil(NN / 256)
#define CAP 5120    // per-bucket edge capacity (expected 4096, sigma~64)
#define CHUNK 2048
#define PBLOCKS 782   // ceil(NE / CHUNK)
#define MMBLOCKS 1563 // ceil(NN / 64)

typedef __attribute__((ext_vector_type(8))) short short8;
typedef __attribute__((ext_vector_type(4))) float f32x4;

static __device__ __forceinline__ unsigned short f2bf(float f) {
    unsigned u = __float_as_uint(f);
    unsigned r = (u + 0x7fffu + ((u >> 16) & 1u)) >> 16;
    return (unsigned short)r;
}
static __device__ __forceinline__ float bf_lo(unsigned u) {
    return __uint_as_float(u << 16);
}
static __device__ __forceinline__ float bf_hi(unsigned u) {
    return __uint_as_float(u & 0xffff0000u);
}
static __device__ __forceinline__ void acc8(float* acc, uint4 v, float nm) {
    acc[0] += bf_lo(v.x) * nm; acc[1] += bf_hi(v.x) * nm;
    acc[2] += bf_lo(v.y) * nm; acc[3] += bf_hi(v.y) * nm;
    acc[4] += bf_lo(v.z) * nm; acc[5] += bf_hi(v.z) * nm;
    acc[6] += bf_lo(v.w) * nm; acc[7] += bf_hi(v.w) * nm;
}

// shared aggregation loop: accumulates neighbors into acc[8] (unroll-4, proven R7/R8)
static __device__ __forceinline__ void agg_loop(const unsigned short* hc,
                                                const int* __restrict__ esrc,
                                                const float* __restrict__ dinv,
                                                int start, int cnt, float dn,
                                                float* acc) {
    int i = 0;
    for (; i + 4 <= cnt; i += 4) {
        int s0 = esrc[start + i];
        int s1 = esrc[start + i + 1];
        int s2 = esrc[start + i + 2];
        int s3 = esrc[start + i + 3];
        float n0 = dinv[s0] * dn, n1 = dinv[s1] * dn;
        float n2 = dinv[s2] * dn, n3 = dinv[s3] * dn;
        uint4 w0 = *(const uint4*)(hc + (long)s0 * 64);
        uint4 w1 = *(const uint4*)(hc + (long)s1 * 64);
        uint4 w2 = *(const uint4*)(hc + (long)s2 * 64);
        uint4 w3 = *(const uint4*)(hc + (long)s3 * 64);
        acc8(acc, w0, n0); acc8(acc, w1, n1); acc8(acc, w2, n2); acc8(acc, w3, n3);
    }
    for (; i < cnt; ++i) {
        int s0 = esrc[start + i];
        float n0 = dinv[s0] * dn;
        uint4 w0 = *(const uint4*)(hc + (long)s0 * 64);
        acc8(acc, w0, n0);
    }
}

// ---------- FAT: blocks [0,PBLOCKS) = edge partition (1-pass); rest = x@W1 ----
// bucket = dst >> 8; pack = (src<<8)|(dst&255)
__global__ __launch_bounds__(256) void k_fat(const int* __restrict__ ei,
                                             int* __restrict__ bcur,
                                             unsigned* __restrict__ ebuf,
                                             const float* __restrict__ x,
                                             const float* __restrict__ W1,
                                             unsigned short* __restrict__ hout) {
    __shared__ __attribute__((aligned(16))) unsigned char smem[17408];  // max(mm Wt 64*136*2, part 2*391*4)
    int tid = threadIdx.x;
    if (blockIdx.x < PBLOCKS) {
        int* lh = (int*)smem;
        int* lbase = lh + NBUCK;
        int e0 = blockIdx.x * CHUNK;
        for (int i = tid; i < NBUCK; i += 256) lh[i] = 0;
        __syncthreads();
        int bs[8]; int rs[8]; unsigned ps[8];
        #pragma unroll
        for (int k = 0; k < 8; ++k) {
            int e = e0 + k * 256 + tid;
            bs[k] = -1;
            if (e < NE) {
                int d = ei[NE + e];
                int s = ei[e];
                int b = d >> 8;
                bs[k] = b;
                rs[k] = atomicAdd(&lh[b], 1);      // local rank (single LDS pass)
                ps[k] = ((unsigned)s << 8) | (unsigned)(d & 255);
            }
        }
        __syncthreads();
        for (int i = tid; i < NBUCK; i += 256) {
            int c = lh[i];
            lbase[i] = c ? atomicAdd(&bcur[i], c) : 0;  // within-bucket offset
        }
        __syncthreads();
        #pragma unroll
        for (int k = 0; k < 8; ++k) {
            if (bs[k] >= 0) {
                int pos = lbase[bs[k]] + rs[k];
                if (pos < CAP)  // safety clamp; never hit for uniform input
                    ebuf[(long)bs[k] * CAP + pos] = ps[k];
            }
        }
    } else {
        // ---- mm128: h1 = x @ W1 -> bf16 ----
        constexpr int K = 128, KP = K + 8;
        unsigned short* Wt = (unsigned short*)smem;  // 64 * 136
        for (int idx = tid; idx < K * 64; idx += 256) {
            int k = idx >> 6, n = idx & 63;
            Wt[n * KP + k] = f2bf(W1[idx]);
        }
        __syncthreads();
        int wave = tid >> 6, lane = tid & 63;
        int m = lane & 15, q = lane >> 4;
        int n0 = (blockIdx.x - PBLOCKS) * 64 + wave * 16;
        f32x4 acc[4] = {{0.f,0.f,0.f,0.f},{0.f,0.f,0.f,0.f},{0.f,0.f,0.f,0.f},{0.f,0.f,0.f,0.f}};
        int row = n0 + m;
        int rowc = row < NN ? row : NN - 1;
        const float* xr = x + (long)rowc * K;
        #pragma unroll
        for (int kk = 0; kk < K / 32; ++kk) {
            const float4* p = (const float4*)(xr + kk * 32 + q * 8);
            float4 v0 = p[0], v1 = p[1];
            float xv[8] = {v0.x, v0.y, v0.z, v0.w, v1.x, v1.y, v1.z, v1.w};
            short8 afrag;
            #pragma unroll
            for (int i2 = 0; i2 < 8; ++i2) afrag[i2] = (short)f2bf(xv[i2]);
            #pragma unroll
            for (int nt = 0; nt < 4; ++nt) {
                const short8* bp = (const short8*)&Wt[(nt * 16 + m) * KP + kk * 32 + q * 8];
                acc[nt] = __builtin_amdgcn_mfma_f32_16x16x32_bf16(afrag, *bp, acc[nt], 0, 0, 0);
            }
        }
        // D layout: col=lane&15, row=(lane>>4)*4+reg  [m89-verified]
        #pragma unroll
        for (int reg = 0; reg < 4; ++reg) {
            int node = n0 + q * 4 + reg;
            if (node < NN) {
                #pragma unroll
                for (int nt = 0; nt < 4; ++nt)
                    hout[(long)node * 64 + nt * 16 + m] = f2bf(acc[nt][reg]);
            }
        }
    }
}

// one block (256 thr) per bucket: count -> shfl-scan -> rowinfo/dinv -> scatter
// rowinfo[node] = (start << 11) | degree   (start < 391*5120 < 2^21, deg < 2^11)
__global__ __launch_bounds__(256) void k_build(const int* __restrict__ bcur,
                                               const unsigned* __restrict__ ebuf,
                                               unsigned* __restrict__ rowinfo,
                                               float* __restrict__ dinv,
                                               int* __restrict__ esrc) {
    __shared__ int cnt[256];
    __shared__ int wsum[4];
    int tid = threadIdx.x;
    int base = blockIdx.x * CAP;
    int nedge = bcur[blockIdx.x];
    if (nedge > CAP) nedge = CAP;
    cnt[tid] = 0;
    __syncthreads();
    for (int j = tid; j < nedge; j += 256)
        atomicAdd(&cnt[ebuf[base + j] & 255u], 1);
    __syncthreads();
    int v = cnt[tid];
    int lane = tid & 63;
    int incl = v;
    #pragma unroll
    for (int off = 1; off < 64; off <<= 1) {
        int t = __shfl_up(incl, off, 64);
        if (lane >= off) incl += t;
    }
    if (lane == 63) wsum[tid >> 6] = incl;
    __syncthreads();
    if (tid == 0) {
        int a = 0;
        #pragma unroll
        for (int w = 0; w < 4; ++w) { int t = wsum[w]; wsum[w] = a; a += t; }
    }
    __syncthreads();
    int ex = incl - v + wsum[tid >> 6];
    int node = blockIdx.x * 256 + tid;
    if (node < NN) {
        rowinfo[node] = ((unsigned)(base + ex) << 11) | (unsigned)v;
        dinv[node] = rsqrtf((float)(v + 1));  // +1 self-loop
    }
    cnt[tid] = base + ex;  // becomes cursor
    __syncthreads();
    for (int j = tid; j < nedge; j += 256) {
        unsigned p = ebuf[base + j];
        int pos = atomicAdd(&cnt[p & 255u], 1);
        esrc[pos] = (int)(p >> 8);
    }
}

// ---------- fused: layer-1 agg (32 nodes/block) + h2 = prelu(agg1)@W2 --------
// NN % 32 == 0 so every block is full.
__global__ __launch_bounds__(256) void k_aggmm(const unsigned* __restrict__ rowinfo,
                                               const int* __restrict__ esrc,
                                               const unsigned short* __restrict__ h,
                                               const float* __restrict__ dinv,
                                               const float* __restrict__ bias,
                                               const float* __restrict__ alpha,
                                               const float* __restrict__ W2,
                                               unsigned short* __restrict__ hout2) {
    __shared__ unsigned short Wt[64 * 72];    // W2 staged: Wt[n*72+k]
    __shared__ unsigned short aggs[32 * 72];  // 32 node-rows of bf16 agg (+8 pad)
    int tid = threadIdx.x;
    for (int idx = tid; idx < 64 * 64; idx += 256) {
        int k = idx >> 6, n = idx & 63;
        Wt[n * 72 + k] = f2bf(W2[idx]);
    }
    int sl = tid & 7;
    int ln = tid >> 3;                  // 0..31 local node
    int node = blockIdx.x * 32 + ln;
    unsigned u = rowinfo[node];
    int start = (int)(u >> 11);
    int cnt = (int)(u & 2047u);
    float dn = dinv[node];
    const unsigned short* hc = h + sl * 8;

    float acc[8];
    {   // self-loop
        uint4 hw = *(const uint4*)(hc + (long)node * 64);
        float d2 = dn * dn;
        acc[0] = bf_lo(hw.x) * d2; acc[1] = bf_hi(hw.x) * d2;
        acc[2] = bf_lo(hw.y) * d2; acc[3] = bf_hi(hw.y) * d2;
        acc[4] = bf_lo(hw.z) * d2; acc[5] = bf_hi(hw.z) * d2;
        acc[6] = bf_lo(hw.w) * d2; acc[7] = bf_hi(hw.w) * d2;
    }
    agg_loop(hc, esrc, dinv, start, cnt, dn, acc);

    float4 blo = *(const float4*)(bias + sl * 8);
    float4 bhi = *(const float4*)(bias + sl * 8 + 4);
    float4 alo = *(const float4*)(alpha + sl * 8);
    float4 ahi = *(const float4*)(alpha + sl * 8 + 4);
    float bb[8] = {blo.x, blo.y, blo.z, blo.w, bhi.x, bhi.y, bhi.z, bhi.w};
    float aa[8] = {alo.x, alo.y, alo.z, alo.w, ahi.x, ahi.y, ahi.z, ahi.w};
    #pragma unroll
    for (int j = 0; j < 8; ++j) {
        float v = acc[j] + bb[j];
        acc[j] = v >= 0.f ? v : aa[j] * v;
    }
    uint4 pk;
    pk.x = (unsigned)f2bf(acc[0]) | ((unsigned)f2bf(acc[1]) << 16);
    pk.y = (unsigned)f2bf(acc[2]) | ((unsigned)f2bf(acc[3]) << 16);
    pk.z = (unsigned)f2bf(acc[4]) | ((unsigned)f2bf(acc[5]) << 16);
    pk.w = (unsigned)f2bf(acc[6]) | ((unsigned)f2bf(acc[7]) << 16);
    *(uint4*)&aggs[ln * 72 + sl * 8] = pk;
    __syncthreads();

    // MFMA: waves 0,1 compute 16 rows each: [16x64] @ [64x64]
    int wave = tid >> 6;
    if (wave < 2) {
        int lane = tid & 63;
        int m = lane & 15, q = lane >> 4;
        int row = wave * 16 + m;
        f32x4 c2[4] = {{0.f,0.f,0.f,0.f},{0.f,0.f,0.f,0.f},{0.f,0.f,0.f,0.f},{0.f,0.f,0.f,0.f}};
        #pragma unroll
        for (int kk = 0; kk < 2; ++kk) {
            short8 afrag = *(const short8*)&aggs[row * 72 + kk * 32 + q * 8];
            #pragma unroll
            for (int nt = 0; nt < 4; ++nt) {
                const short8* bp = (const short8*)&Wt[(nt * 16 + m) * 72 + kk * 32 + q * 8];
                c2[nt] = __builtin_amdgcn_mfma_f32_16x16x32_bf16(afrag, *bp, c2[nt], 0, 0, 0);
            }
        }
        #pragma unroll
        for (int reg = 0; reg < 4; ++reg) {
            int nd = blockIdx.x * 32 + wave * 16 + q * 4 + reg;
            #pragma unroll
            for (int nt = 0; nt < 4; ++nt)
                hout2[(long)nd * 64 + nt * 16 + m] = f2bf(c2[nt][reg]);
        }
    }
}

// ---------- final aggregation: 8 lanes/node, fp32 out ------------------------
__global__ __launch_bounds__(256) void k_agg2(const unsigned* __restrict__ rowinfo,
                                              const int* __restrict__ esrc,
                                              const unsigned short* __restrict__ h,
                                              const float* __restrict__ dinv,
                                              const float* __restrict__ bias,
                                              const float* __restrict__ alpha,
                                              float* __restrict__ out) {
    int sl = threadIdx.x & 7;
    int node = blockIdx.x * 32 + (threadIdx.x >> 3);
    unsigned u = rowinfo[node];
    int start = (int)(u >> 11);
    int cnt = (int)(u & 2047u);
    float dn = dinv[node];
    const unsigned short* hc = h + sl * 8;

    float acc[8];
    {   // self-loop
        uint4 hw = *(const uint4*)(hc + (long)node * 64);
        float d2 = dn * dn;
        acc[0] = bf_lo(hw.x) * d2; acc[1] = bf_hi(hw.x) * d2;
        acc[2] = bf_lo(hw.y) * d2; acc[3] = bf_hi(hw.y) * d2;
        acc[4] = bf_lo(hw.z) * d2; acc[5] = bf_hi(hw.z) * d2;
        acc[6] = bf_lo(hw.w) * d2; acc[7] = bf_hi(hw.w) * d2;
    }
    agg_loop(hc, esrc, dinv, start, cnt, dn, acc);

    float4 blo = *(const float4*)(bias + sl * 8);
    float4 bhi = *(const float4*)(bias + sl * 8 + 4);
    float4 alo = *(const float4*)(alpha + sl * 8);
    float4 ahi = *(const float4*)(alpha + sl * 8 + 4);
    float bb[8] = {blo.x, blo.y, blo.z, blo.w, bhi.x, bhi.y, bhi.z, bhi.w};
    float aa[8] = {alo.x, alo.y, alo.z, alo.w, ahi.x, ahi.y, ahi.z, ahi.w};
    #pragma unroll
    for (int j = 0; j < 8; ++j) {
        float v = acc[j] + bb[j];
        acc[j] = v >= 0.f ? v : aa[j] * v;
    }
    float* op = out + (long)node * 64 + sl * 8;
    *(float4*)op = make_float4(acc[0], acc[1], acc[2], acc[3]);
    *(float4*)(op + 4) = make_float4(acc[4], acc[5], acc[6], acc[7]);
}

extern "C" void kernel_launch(void* const* d_in, const int* in_sizes, int n_in,
                              void* d_out, int out_size, void* d_ws, size_t ws_size,
                              hipStream_t stream) {
    const float* x     = (const float*)d_in[0];
    const int*   ei    = (const int*)d_in[1];
    const float* W1    = (const float*)d_in[2];
    const float* b1    = (const float*)d_in[3];
    const float* W2    = (const float*)d_in[4];
    const float* b2    = (const float*)d_in[5];
    const float* alpha = (const float*)d_in[6];
    float* out = (float*)d_out;

    char* ws = (char*)d_ws;
    float*    dinv      = (float*)(ws);                      //        0: 400,384
    unsigned* rowinfo   = (unsigned*)(ws + 400384);          //   400384: 400,384
    int*      bcur      = (int*)(ws + 800768);               //   800768: 2,048
    int*      esrc      = (int*)(ws + 802816);               //   802816: 8,007,680 (391*CAP)
    unsigned short* hbf = (unsigned short*)(ws + 8810496);   //  8810496: 12,800,000
    unsigned* ebuf      = (unsigned*)(ws + 21610496);        // 21610496: region max(8.0M, 12.8M)
    unsigned short* hbf2 = (unsigned short*)(ws + 21610496); // alias ebuf (dead after k_build)
    // total: 34,410,496 B

    (void)hipMemsetAsync(bcur, 0, NBUCK * sizeof(int), stream);
    // edge partition (782 blocks, single-pass) overlapped with x@W1 (1563 blocks)
    k_fat<<<PBLOCKS + MMBLOCKS, 256, 0, stream>>>(ei, bcur, ebuf, x, W1, hbf);
    k_build<<<NBUCK, 256, 0, stream>>>(bcur, ebuf, rowinfo, dinv, esrc);
    // layer-1 agg fused with layer-2 matmul (h2 -> hbf2, aliases dead ebuf)
    k_aggmm<<<NN / 32, 256, 0, stream>>>(rowinfo, esrc, hbf, dinv, b1, alpha, W2, hbf2);
    // layer-2 aggregation -> fp32 out
    k_agg2<<<NN / 32, 256, 0, stream>>>(rowinfo, esrc, hbf2, dinv, b2, alpha, out);
}